// Round 13
// baseline (340.294 us; speedup 1.0000x reference)
//
#include <hip/hip_runtime.h>

typedef unsigned short u16;
typedef unsigned int u32;

#define N_NODES 50000
#define N_EDGES 1600000
#define CH 128
#define CHW 64          // u32 words per packed-bf16 row
#define NG 512
#define CAP 128         // bucket capacity per node (Poisson(32): P(>=128) ~ 1e-43)
#define PAD 136         // LDS row stride in bf16 elems (272B: 16B-aligned, bank-spread)
#define NBINS 196       // ceil(50000/256)
#define BINCAP 12288    // slots per bin (expect ~8192, max ~8650)
#define NSCAT 512       // edge_scatter workgroups
#define ECHUNK 3125     // edges per workgroup (512*3125 = 1.6M exact)

typedef __bf16 bf16x8 __attribute__((ext_vector_type(8)));
typedef float f32x4 __attribute__((ext_vector_type(4)));

// ---- workspace byte offsets (total ~54.9 MB) ----
#define OFF_DEG 0ull              // 200,000 B
#define OFF_BUCKET 200192ull      // u16 bucket, 12,800,000 B
#define OFF_XB 13000192ull        // 12.8 MB packed-bf16 x; reused as h2
#define OFF_HSUM 25800192ull      // 12.8 MB; binned edges (9.6 MB) overlap here pre-agg
#define OFF_H1 38600192ull        // 12.8 MB
#define OFF_POOL 51400192ull      // 262,144 B
#define OFF_GS 51662336ull        // 2,048 B
#define OFF_GE 51664384ull        // 2,048 B
#define OFF_WT 51666432ull        // 4 x 32,768 B bf16 transposed weights [n][k]
#define OFF_BC 51797504ull        // 4 x 512 B fp32 biases
#define OFF_WF1 51799552ull       // 65,536 B fp32
#define OFF_BF1 51865088ull       // 512 B
#define OFF_WF2 51865600ull       // 3,072 B
#define OFF_BF2 51868672ull       // 32 B
#define OFF_BCUR 51868928ull      // 1,024 B bin cursors

__device__ __forceinline__ float bflo(u32 v) { return __builtin_bit_cast(float, v << 16); }
__device__ __forceinline__ float bfhi(u32 v) { return __builtin_bit_cast(float, v & 0xffff0000u); }
__device__ __forceinline__ float bf2f(u16 v) { return __builtin_bit_cast(float, ((u32)v) << 16); }
__device__ __forceinline__ u16 f2bf(float f) {
    u32 x = __builtin_bit_cast(u32, f);
    x += 0x7fffu + ((x >> 16) & 1u);   // RNE
    return (u16)(x >> 16);
}
__device__ __forceinline__ u32 pack2(float a, float b) {
    return (u32)f2bf(a) | ((u32)f2bf(b) << 16);
}
__device__ __forceinline__ bool probe_bf16(u32 w0) {
    u32 ex = (w0 >> 7) & 0xFFu;
    bool ok = ((w0 & 0x7FFFu) == 0u) || (ex >= 0x70u && ex <= 0x8Fu);
    return __popcll(__ballot(ok)) >= 48;
}
__device__ __forceinline__ float loadf(const void* p, int i, bool isbf) {
    return isbf ? bf2f(((const u16*)p)[i]) : ((const float*)p)[i];
}

// ---------------- param canonicalization + all small-buffer inits ----------------
// blocks 0-3: LDS tile transpose of W0..W3 -> bf16 [n][k]
// blocks 4+: biases/head copy (fp32) + zero binCursor + init gstart/gend
__global__ __launch_bounds__(256) void prep_params(char* ws,
                                                   const void* W0, const void* W1,
                                                   const void* W2, const void* W3,
                                                   const void* b0, const void* b1,
                                                   const void* b2, const void* b3,
                                                   const void* Wf1, const void* bf1,
                                                   const void* Wf2, const void* bf2) {
    __shared__ float tile[128 * 129];
    int tid = threadIdx.x;
    int lane = tid & 63;
    bool isbf = probe_bf16(((const u32*)W0)[lane]);
    int b = blockIdx.x;
    if (b < 4) {
        const void* src = (b == 0) ? W0 : (b == 1) ? W1 : (b == 2) ? W2 : W3;
#pragma unroll 4
        for (int it = 0; it < 64; ++it) {        // coalesced read W[k][n]
            int idx = it * 256 + tid;
            int k = idx >> 7, n = idx & 127;
            tile[k * 129 + n] = loadf(src, idx, isbf);
        }
        __syncthreads();
        u16* Wt = (u16*)(ws + OFF_WT) + b * 16384;
#pragma unroll 4
        for (int it = 0; it < 64; ++it) {        // coalesced write Wt[n][k]; 129-stride = conflict-free
            int o = it * 256 + tid;
            int n = o >> 7, k = o & 127;
            Wt[o] = f2bf(tile[k * 129 + n]);
        }
        return;
    }
    int idx = (b - 4) * 256 + tid;
    float* bc = (float*)(ws + OFF_BC);
    float* Wf1c = (float*)(ws + OFF_WF1);
    float* bf1c = (float*)(ws + OFF_BF1);
    float* Wf2c = (float*)(ws + OFF_WF2);
    float* bf2c = (float*)(ws + OFF_BF2);
    int* binCursor = (int*)(ws + OFF_BCUR);
    int* gstart = (int*)(ws + OFF_GS);
    int* gend = (int*)(ws + OFF_GE);
    if (idx < 512) {                              // 4 biases
        int j = idx >> 7, c = idx & 127;
        const void* src = (j == 0) ? b0 : (j == 1) ? b1 : (j == 2) ? b2 : b3;
        bc[idx] = loadf(src, c, isbf);
    } else if (idx < 16896) {
        Wf1c[idx - 512] = loadf(Wf1, idx - 512, isbf);
    } else if (idx < 17024) {
        bf1c[idx - 16896] = loadf(bf1, idx - 16896, isbf);
    } else if (idx < 17792) {
        Wf2c[idx - 17024] = loadf(Wf2, idx - 17024, isbf);
    } else if (idx < 17798) {
        bf2c[idx - 17792] = loadf(bf2, idx - 17792, isbf);
    } else if (idx < 18054) {
        binCursor[idx - 17798] = 0;
    } else if (idx < 18566) {
        gstart[idx - 18054] = 0x7F7F7F7F;
    } else if (idx < 19078) {
        gend[idx - 18566] = 0;
    }
}

// ---------------- x -> packed bf16 + graph ranges (merged) ----------------
__global__ __launch_bounds__(256) void cvt_gb(const u32* __restrict__ x, u32* __restrict__ xb,
                                              const int* __restrict__ batch,
                                              int* __restrict__ gstart,
                                              int* __restrict__ gend) {
    int lane = threadIdx.x & 63;
    bool isbf = probe_bf16(x[lane]);
    int i = blockIdx.x * 256 + threadIdx.x;
    if (i < N_NODES * CHW) {
        if (isbf) {
            xb[i] = x[i];
        } else {
            float2 v = ((const float2*)x)[i];
            xb[i] = pack2(v.x, v.y);
        }
    }
    if (blockIdx.x < 196) {                      // graph_bounds part (50000 nodes / 256)
        u32 hiw = ((const u32*)batch)[2 * (12500 + lane) + 1];
        bool i64 = __popcll(__ballot(hiw == 0u)) >= 48;
        int n = blockIdx.x * 256 + threadIdx.x;
        if (n < N_NODES) {
            int g = i64 ? batch[2 * n] : batch[n];
            atomicMin(&gstart[g], n);
            atomicMax(&gend[g], n + 1);
        }
    }
}

// ---------------- edge binning by dst>>8, single global read via LDS stash ----------------
__global__ __launch_bounds__(256) void edge_scatter(const int* __restrict__ ei,
                                                    int* __restrict__ binCursor,
                                                    u32* __restrict__ binned) {
    __shared__ u32 lhist[256];
    __shared__ u32 lbase[256];
    __shared__ u32 lcur[256];
    __shared__ u32 stash[ECHUNK];
    int tid = threadIdx.x, wg = blockIdx.x;
    int lane = tid & 63;
    u32 hiw = ((const u32*)ei)[2 * lane + 1];        // int64 => high words all 0
    bool i64 = __popcll(__ballot(hiw == 0u)) >= 48;
    int e0 = wg * ECHUNK;
    lhist[tid] = 0; lcur[tid] = 0;
    __syncthreads();
    for (int li = tid; li < ECHUNK; li += 256) {
        int e = e0 + li;
        int s, d;
        if (i64) { s = ei[2 * e]; d = ei[2 * N_EDGES + 2 * e]; }
        else     { s = ei[e];     d = ei[N_EDGES + e]; }
        stash[li] = ((u32)d << 16) | (u32)s;
        atomicAdd(&lhist[d >> 8], 1u);
    }
    __syncthreads();
    u32 c = lhist[tid];
    if (c) lbase[tid] = (u32)atomicAdd(&binCursor[tid], (int)c);
    __syncthreads();
    for (int li = tid; li < ECHUNK; li += 256) {
        u32 w = stash[li];
        int b = (int)(w >> 24);                  // (dst>>8): dst = w>>16, bin = dst>>8
        u32 p = atomicAdd(&lcur[b], 1u);
        binned[(size_t)b * BINCAP + lbase[b] + p] = w;
    }
}

// ---------------- bucket build from binned edges ----------------
__global__ __launch_bounds__(256) void fill_from_binned(const int* __restrict__ binCursor,
                                                        const u32* __restrict__ binned,
                                                        int* __restrict__ deg,
                                                        u16* __restrict__ bucket) {
    __shared__ u32 ldeg[256];
    int tid = threadIdx.x, b = blockIdx.x;
    int cnt = binCursor[b];
    ldeg[tid] = 0;
    __syncthreads();
    const u32* bp = binned + (size_t)b * BINCAP;
    for (int i = tid; i < cnt; i += 256) {
        u32 w = bp[i];
        u32 dl = (w >> 16) & 255u;
        u32 pos = atomicAdd(&ldeg[dl], 1u);
        if (pos < CAP) bucket[(size_t)(w >> 16) * CAP + pos] = (u16)(w & 0xFFFFu);
    }
    __syncthreads();
    int node = b * 256 + tid;
    if (node < N_NODES) deg[node] = (int)ldeg[tid];
}

// ---------------- aggregation v3: uint4 gathers, up to 8 loads (32 edges) in flight ----------------
__global__ __launch_bounds__(256) void agg_kernel(const u32* __restrict__ h,
                                                  const int* __restrict__ deg,
                                                  const u16* __restrict__ bucket,
                                                  u32* __restrict__ out) {
    int w = threadIdx.x >> 6, lane = threadIdx.x & 63;
    int node = blockIdx.x * 4 + w;
    if (node >= N_NODES) return;
    int sub = lane >> 4, q = lane & 15;
    const uint4* h4 = (const uint4*)h;
    float acc[8];
    {   // self row, counted once (sub 0 only)
        uint4 sv = make_uint4(0u, 0u, 0u, 0u);
        if (sub == 0) sv = h4[(size_t)node * 16 + q];
        acc[0] = bflo(sv.x); acc[1] = bfhi(sv.x);
        acc[2] = bflo(sv.y); acc[3] = bfhi(sv.y);
        acc[4] = bflo(sv.z); acc[5] = bfhi(sv.z);
        acc[6] = bflo(sv.w); acc[7] = bfhi(sv.w);
    }
    int d = deg[node];
    d = d > CAP ? CAP : d;
    const u32* bkw = (const u32*)(bucket + (size_t)node * CAP);
    const u32 sh = (u32)(sub & 1) * 16u;
    const int widx = sub >> 1;
    int j = 0;
    for (; j + 32 <= d; j += 32) {           // 32 edges: 8 independent 4-row gathers in flight
        int base = j >> 1;
        u32 wd0 = bkw[base + widx];
        u32 wd1 = bkw[base + 2 + widx];
        u32 wd2 = bkw[base + 4 + widx];
        u32 wd3 = bkw[base + 6 + widx];
        u32 wd4 = bkw[base + 8 + widx];
        u32 wd5 = bkw[base + 10 + widx];
        u32 wd6 = bkw[base + 12 + widx];
        u32 wd7 = bkw[base + 14 + widx];
        uint4 v0 = h4[(size_t)((wd0 >> sh) & 0xFFFFu) * 16 + q];
        uint4 v1 = h4[(size_t)((wd1 >> sh) & 0xFFFFu) * 16 + q];
        uint4 v2 = h4[(size_t)((wd2 >> sh) & 0xFFFFu) * 16 + q];
        uint4 v3 = h4[(size_t)((wd3 >> sh) & 0xFFFFu) * 16 + q];
        uint4 v4 = h4[(size_t)((wd4 >> sh) & 0xFFFFu) * 16 + q];
        uint4 v5 = h4[(size_t)((wd5 >> sh) & 0xFFFFu) * 16 + q];
        uint4 v6 = h4[(size_t)((wd6 >> sh) & 0xFFFFu) * 16 + q];
        uint4 v7 = h4[(size_t)((wd7 >> sh) & 0xFFFFu) * 16 + q];
        acc[0] += bflo(v0.x) + bflo(v1.x) + bflo(v2.x) + bflo(v3.x)
                + bflo(v4.x) + bflo(v5.x) + bflo(v6.x) + bflo(v7.x);
        acc[1] += bfhi(v0.x) + bfhi(v1.x) + bfhi(v2.x) + bfhi(v3.x)
                + bfhi(v4.x) + bfhi(v5.x) + bfhi(v6.x) + bfhi(v7.x);
        acc[2] += bflo(v0.y) + bflo(v1.y) + bflo(v2.y) + bflo(v3.y)
                + bflo(v4.y) + bflo(v5.y) + bflo(v6.y) + bflo(v7.y);
        acc[3] += bfhi(v0.y) + bfhi(v1.y) + bfhi(v2.y) + bfhi(v3.y)
                + bfhi(v4.y) + bfhi(v5.y) + bfhi(v6.y) + bfhi(v7.y);
        acc[4] += bflo(v0.z) + bflo(v1.z) + bflo(v2.z) + bflo(v3.z)
                + bflo(v4.z) + bflo(v5.z) + bflo(v6.z) + bflo(v7.z);
        acc[5] += bfhi(v0.z) + bfhi(v1.z) + bfhi(v2.z) + bfhi(v3.z)
                + bfhi(v4.z) + bfhi(v5.z) + bfhi(v6.z) + bfhi(v7.z);
        acc[6] += bflo(v0.w) + bflo(v1.w) + bflo(v2.w) + bflo(v3.w)
                + bflo(v4.w) + bflo(v5.w) + bflo(v6.w) + bflo(v7.w);
        acc[7] += bfhi(v0.w) + bfhi(v1.w) + bfhi(v2.w) + bfhi(v3.w)
                + bfhi(v4.w) + bfhi(v5.w) + bfhi(v6.w) + bfhi(v7.w);
    }
    for (; j + 16 <= d; j += 16) {           // 16 edges: 4 gathers
        int base = j >> 1;
        u32 wd0 = bkw[base + widx];
        u32 wd1 = bkw[base + 2 + widx];
        u32 wd2 = bkw[base + 4 + widx];
        u32 wd3 = bkw[base + 6 + widx];
        uint4 v0 = h4[(size_t)((wd0 >> sh) & 0xFFFFu) * 16 + q];
        uint4 v1 = h4[(size_t)((wd1 >> sh) & 0xFFFFu) * 16 + q];
        uint4 v2 = h4[(size_t)((wd2 >> sh) & 0xFFFFu) * 16 + q];
        uint4 v3 = h4[(size_t)((wd3 >> sh) & 0xFFFFu) * 16 + q];
        acc[0] += bflo(v0.x) + bflo(v1.x) + bflo(v2.x) + bflo(v3.x);
        acc[1] += bfhi(v0.x) + bfhi(v1.x) + bfhi(v2.x) + bfhi(v3.x);
        acc[2] += bflo(v0.y) + bflo(v1.y) + bflo(v2.y) + bflo(v3.y);
        acc[3] += bfhi(v0.y) + bfhi(v1.y) + bfhi(v2.y) + bfhi(v3.y);
        acc[4] += bflo(v0.z) + bflo(v1.z) + bflo(v2.z) + bflo(v3.z);
        acc[5] += bfhi(v0.z) + bfhi(v1.z) + bfhi(v2.z) + bfhi(v3.z);
        acc[6] += bflo(v0.w) + bflo(v1.w) + bflo(v2.w) + bflo(v3.w);
        acc[7] += bfhi(v0.w) + bfhi(v1.w) + bfhi(v2.w) + bfhi(v3.w);
    }
    for (; j + 4 <= d; j += 4) {             // 4-edge groups
        u32 wd = bkw[(j >> 1) + widx];
        uint4 v = h4[(size_t)((wd >> sh) & 0xFFFFu) * 16 + q];
        acc[0] += bflo(v.x); acc[1] += bfhi(v.x);
        acc[2] += bflo(v.y); acc[3] += bfhi(v.y);
        acc[4] += bflo(v.z); acc[5] += bfhi(v.z);
        acc[6] += bflo(v.w); acc[7] += bfhi(v.w);
    }
    if (j + sub < d) {                       // tail (<4 edges), predicated per sub
        int e = j + sub;
        u32 wd = bkw[e >> 1];
        u32 id = (wd >> ((u32)(e & 1) * 16u)) & 0xFFFFu;
        uint4 v = h4[(size_t)id * 16 + q];
        acc[0] += bflo(v.x); acc[1] += bfhi(v.x);
        acc[2] += bflo(v.y); acc[3] += bfhi(v.y);
        acc[4] += bflo(v.z); acc[5] += bfhi(v.z);
        acc[6] += bflo(v.w); acc[7] += bfhi(v.w);
    }
#pragma unroll
    for (int c = 0; c < 8; ++c) {            // butterfly across the 4 sub-groups
        acc[c] += __shfl_xor(acc[c], 16, 64);
        acc[c] += __shfl_xor(acc[c], 32, 64);
    }
    if (sub == 0) {
        uint4 o;
        o.x = pack2(acc[0], acc[1]);
        o.y = pack2(acc[2], acc[3]);
        o.z = pack2(acc[4], acc[5]);
        o.w = pack2(acc[6], acc[7]);
        ((uint4*)out)[(size_t)node * 16 + q] = o;
    }
}

// ---------------- fused 2-layer MLP: out = relu(relu(in@Wa+ba)@Wb+bb), bf16 MFMA ----------------
__global__ __launch_bounds__(256) void mlp_kernel(const u16* __restrict__ in,
                                                  const u16* __restrict__ Wta,
                                                  const float* __restrict__ ba,
                                                  const u16* __restrict__ Wtb,
                                                  const float* __restrict__ bb,
                                                  u16* __restrict__ out,
                                                  int nrows) {
    __shared__ __align__(16) u16 Wlds[128 * PAD];  // [n][k]
    __shared__ __align__(16) u16 tlds[64 * PAD];   // per-wave 16-row staging [r][k]
    const int tid = threadIdx.x;
    const int w = tid >> 6;
    const int lane = tid & 63;
    const int n16 = lane & 15;
    const int quad = lane >> 4;
    const int row0 = blockIdx.x * 64 + w * 16;
    const bool active = row0 < nrows;

    {   // stage Wa: 2048 x 16B copies, 8 per thread
        const uint4* wsrc = (const uint4*)Wta;
#pragma unroll
        for (int it = 0; it < 8; ++it) {
            int idx = tid + it * 256;
            int n = idx >> 4, c = idx & 15;
            *(uint4*)&Wlds[n * PAD + c * 8] = wsrc[idx];
        }
    }
    __syncthreads();

    f32x4 acc[8];
    bf16x8 afrag[4];
    if (active) {
        const u16* rowp = in + (size_t)(row0 + n16) * CH + quad * 8;
#pragma unroll
        for (int ks = 0; ks < 4; ++ks)
            afrag[ks] = *(const bf16x8*)(rowp + ks * 32);
#pragma unroll
        for (int ct = 0; ct < 8; ++ct) {
            f32x4 a = {0.f, 0.f, 0.f, 0.f};
#pragma unroll
            for (int ks = 0; ks < 4; ++ks) {
                bf16x8 b = *(const bf16x8*)&Wlds[(u32)(ct * 16 + n16) * PAD + ks * 32 + quad * 8];
                a = __builtin_amdgcn_mfma_f32_16x16x32_bf16(afrag[ks], b, a, 0, 0, 0);
            }
            acc[ct] = a;
        }
#pragma unroll
        for (int ct = 0; ct < 8; ++ct) {
            float bv = ba[ct * 16 + n16];
#pragma unroll
            for (int r = 0; r < 4; ++r) {
                float v = fmaxf(acc[ct][r] + bv, 0.f);
                tlds[(w * 16 + quad * 4 + r) * PAD + ct * 16 + n16] = f2bf(v);
            }
        }
    }
    __syncthreads();
    {   // stage Wb
        const uint4* wsrc = (const uint4*)Wtb;
#pragma unroll
        for (int it = 0; it < 8; ++it) {
            int idx = tid + it * 256;
            int n = idx >> 4, c = idx & 15;
            *(uint4*)&Wlds[n * PAD + c * 8] = wsrc[idx];
        }
    }
    __syncthreads();

    if (active) {
#pragma unroll
        for (int ks = 0; ks < 4; ++ks)
            afrag[ks] = *(const bf16x8*)&tlds[(u32)(w * 16 + n16) * PAD + ks * 32 + quad * 8];
#pragma unroll
        for (int ct = 0; ct < 8; ++ct) {
            f32x4 a = {0.f, 0.f, 0.f, 0.f};
#pragma unroll
            for (int ks = 0; ks < 4; ++ks) {
                bf16x8 b = *(const bf16x8*)&Wlds[(u32)(ct * 16 + n16) * PAD + ks * 32 + quad * 8];
                a = __builtin_amdgcn_mfma_f32_16x16x32_bf16(afrag[ks], b, a, 0, 0, 0);
            }
            acc[ct] = a;
        }
#pragma unroll
        for (int ct = 0; ct < 8; ++ct) {
            float bv = bb[ct * 16 + n16];
#pragma unroll
            for (int r = 0; r < 4; ++r) {
                float v = fmaxf(acc[ct][r] + bv, 0.f);
                tlds[(w * 16 + quad * 4 + r) * PAD + ct * 16 + n16] = f2bf(v);
            }
        }
        u32* outw = (u32*)out;
        for (int r = 0; r < 16; ++r) {
            u32 v = *(const u32*)&tlds[(w * 16 + r) * PAD + lane * 2];
            outw[(size_t)(row0 + r) * CHW + lane] = v;
        }
    }
}

// ---------------- mean pool v2: sub-group uint4 gathers + butterfly ----------------
__global__ __launch_bounds__(256) void pool_kernel(const u32* __restrict__ h,
                                                   const int* __restrict__ gstart,
                                                   const int* __restrict__ gend,
                                                   float* __restrict__ pooled) {
    int w = threadIdx.x >> 6, lane = threadIdx.x & 63;
    int g = blockIdx.x * 4 + w;
    if (g >= NG) return;
    int sub = lane >> 4, q = lane & 15;
    int s = gstart[g], e = gend[g];
    const uint4* h4 = (const uint4*)h;
    float acc[8] = {0.f, 0.f, 0.f, 0.f, 0.f, 0.f, 0.f, 0.f};
    int i = s + sub;
    for (; i + 4 < e; i += 8) {              // 2 rows in flight per sub (8 per wave)
        uint4 v0 = h4[(size_t)i * 16 + q];
        uint4 v1 = h4[(size_t)(i + 4) * 16 + q];
        acc[0] += bflo(v0.x) + bflo(v1.x); acc[1] += bfhi(v0.x) + bfhi(v1.x);
        acc[2] += bflo(v0.y) + bflo(v1.y); acc[3] += bfhi(v0.y) + bfhi(v1.y);
        acc[4] += bflo(v0.z) + bflo(v1.z); acc[5] += bfhi(v0.z) + bfhi(v1.z);
        acc[6] += bflo(v0.w) + bflo(v1.w); acc[7] += bfhi(v0.w) + bfhi(v1.w);
    }
    for (; i < e; i += 4) {
        uint4 v = h4[(size_t)i * 16 + q];
        acc[0] += bflo(v.x); acc[1] += bfhi(v.x);
        acc[2] += bflo(v.y); acc[3] += bfhi(v.y);
        acc[4] += bflo(v.z); acc[5] += bfhi(v.z);
        acc[6] += bflo(v.w); acc[7] += bfhi(v.w);
    }
#pragma unroll
    for (int c = 0; c < 8; ++c) {
        acc[c] += __shfl_xor(acc[c], 16, 64);
        acc[c] += __shfl_xor(acc[c], 32, 64);
    }
    if (sub == 0) {
        float inv = 1.f / (float)((s < e) ? (e - s) : 1);
        float4 a0 = make_float4(acc[0] * inv, acc[1] * inv, acc[2] * inv, acc[3] * inv);
        float4 a1 = make_float4(acc[4] * inv, acc[5] * inv, acc[6] * inv, acc[7] * inv);
        ((float4*)pooled)[(size_t)g * 32 + q * 2] = a0;
        ((float4*)pooled)[(size_t)g * 32 + q * 2 + 1] = a1;
    }
}

// ---------------- head: sigmoid(relu(pooled@Wf1+bf1)@Wf2+bf2), fp32, fp32 out ----------------
__global__ __launch_bounds__(256) void final_kernel(const float* __restrict__ pooled,
                                                    const float* __restrict__ Wf1,
                                                    const float* __restrict__ bf1,
                                                    const float* __restrict__ Wf2,
                                                    const float* __restrict__ bf2v,
                                                    float* __restrict__ out) {
    __shared__ float rowb[4][128];
    __shared__ float tb[4][128];
    int w = threadIdx.x >> 6, lane = threadIdx.x & 63;
    int g = blockIdx.x * 4 + w;  // grid exact: 128 * 4 = 512
    float2 rv = ((const float2*)pooled)[(size_t)g * CHW + lane];
    rowb[w][2 * lane] = rv.x;
    rowb[w][2 * lane + 1] = rv.y;
    __syncthreads();
#pragma unroll
    for (int jj = 0; jj < 2; ++jj) {
        int j = lane + jj * 64;
        float a = bf1[j];
        for (int k = 0; k < 128; ++k) a += rowb[w][k] * Wf1[k * 128 + j];
        tb[w][j] = fmaxf(a, 0.f);
    }
    __syncthreads();
    if (lane < 6) {
        float a = bf2v[lane];
        for (int k = 0; k < 128; ++k) a += tb[w][k] * Wf2[k * 6 + lane];
        out[g * 6 + lane] = 1.f / (1.f + __expf(-a));
    }
}

extern "C" void kernel_launch(void* const* d_in, const int* in_sizes, int n_in,
                              void* d_out, int out_size, void* d_ws, size_t ws_size,
                              hipStream_t stream) {
    const u32* x = (const u32*)d_in[0];
    const int* ei = (const int*)d_in[1];
    const int* batch = (const int*)d_in[2];
    float* out = (float*)d_out;

    char* ws = (char*)d_ws;
    int* deg = (int*)(ws + OFF_DEG);
    u16* bucket = (u16*)(ws + OFF_BUCKET);
    u32* XB = (u32*)(ws + OFF_XB);
    u32* HSUM = (u32*)(ws + OFF_HSUM);
    u32* H1 = (u32*)(ws + OFF_H1);
    float* pooled = (float*)(ws + OFF_POOL);
    int* gstart = (int*)(ws + OFF_GS);
    int* gend = (int*)(ws + OFF_GE);
    u16* Wt = (u16*)(ws + OFF_WT);
    float* bc = (float*)(ws + OFF_BC);
    float* Wf1c = (float*)(ws + OFF_WF1);
    float* bf1c = (float*)(ws + OFF_BF1);
    float* Wf2c = (float*)(ws + OFF_WF2);
    float* bf2c = (float*)(ws + OFF_BF2);
    int* binCursor = (int*)(ws + OFF_BCUR);
    u32* binned = HSUM;

    // prep also zeroes binCursor and inits gstart/gend (stream order guarantees visibility)
    prep_params<<<79, 256, 0, stream>>>(ws,
        d_in[3], d_in[5], d_in[7], d_in[9],      // W1a, W1b, W2a, W2b
        d_in[4], d_in[6], d_in[8], d_in[10],     // b1a, b1b, b2a, b2b
        d_in[11], d_in[12], d_in[13], d_in[14]); // Wf1, bf1, Wf2, bf2
    cvt_gb<<<(N_NODES * CHW) / 256, 256, 0, stream>>>(x, XB, batch, gstart, gend);
    edge_scatter<<<NSCAT, 256, 0, stream>>>(ei, binCursor, binned);
    fill_from_binned<<<NBINS, 256, 0, stream>>>(binCursor, binned, deg, bucket);

    // layer 1: XB -> HSUM -> H1   (binned consumed; HSUM safely overwritten)
    agg_kernel<<<(N_NODES + 3) / 4, 256, 0, stream>>>(XB, deg, bucket, HSUM);
    mlp_kernel<<<(N_NODES + 63) / 64, 256, 0, stream>>>((const u16*)HSUM, Wt, bc,
                                                        Wt + 16384, bc + 128, (u16*)H1, N_NODES);
    // layer 2: H1 -> HSUM -> XB (reused as h2)
    agg_kernel<<<(N_NODES + 3) / 4, 256, 0, stream>>>(H1, deg, bucket, HSUM);
    mlp_kernel<<<(N_NODES + 63) / 64, 256, 0, stream>>>((const u16*)HSUM, Wt + 32768, bc + 256,
                                                        Wt + 49152, bc + 384, (u16*)XB, N_NODES);
    // pool + head
    pool_kernel<<<(NG + 3) / 4, 256, 0, stream>>>(XB, gstart, gend, pooled);
    final_kernel<<<NG / 4, 256, 0, stream>>>(pooled, Wf1c, bf1c, Wf2c, bf2c, out);
}